// Round 6
// baseline (558.954 us; speedup 1.0000x reference)
//
#include <hip/hip_runtime.h>
#include <hip/hip_bf16.h>

#define NNODES 50000
#define NEDGES 320000
#define EMB 128
#define DIN 192
#define NB 3
#define LAM 0.01f
#define LN_EPS 1e-5f
#define PI_F 3.14159265358979323846f

#define SCAN_B 196                        // 196*256 = 50176 >= NNODES
#define SCAN_N (SCAN_B * 256)

typedef __attribute__((ext_vector_type(8))) short v8s;
typedef __attribute__((ext_vector_type(4))) float v4f;
typedef __attribute__((ext_vector_type(2))) float v2f;

// ---- workspace layout (4B-unit offsets) ----
#define WS_ESUM 0
#define WS_WB   16                        // Wb bf16 [3][6][16][64][8]
#define WS_G2B  (WS_WB + 73728)           // G2b bf16 [3][8][8][64][8]
#define WS_PHI  (WS_G2B + 49152)          // Phi [768][128]
#define WS_M    (WS_PHI + 98304)          // M [128][128]
#define WS_BB   (WS_M + 16384)            // bb [768]
#define WS_GB2  (WS_BB + 768)             // g_b2 [128]
#define WS_CK   (WS_GB2 + 128)            // c_k [3][128]
#define WS_EN   (WS_CK + 384)             // energies [NE]
#define WS_NORM (WS_EN + NEDGES)          // node norms [NN]
#define WS_CNT  (WS_NORM + NNODES)        // int counts [SCAN_N]
#define WS_CUR  (WS_CNT + SCAN_N)         // int cursors [SCAN_N]
#define WS_LOOK (WS_CUR + SCAN_N)         // u64 lookback state [256] (512 ints)
#define WS_EIDS (WS_LOOK + 512)           // int sorted edge ids [NE]

__device__ __forceinline__ unsigned pk2(float a, float b) {
  __hip_bfloat162 h2 = __float22bfloat162_rn(make_float2(a, b));
  return *reinterpret_cast<unsigned*>(&h2);
}

__device__ __forceinline__ void atomic2(float* dp, float a, float b) {
#if __has_builtin(__builtin_amdgcn_flat_atomic_fadd_v2f32)
  v2f val; val.x = a; val.y = b;
  __builtin_amdgcn_flat_atomic_fadd_v2f32((v2f*)dp, val);
#else
  atomicAdd(dp, a); atomicAdd(dp + 1, b);
#endif
}

// ---- P1: wfull(576) | m(64) | phi(384) | norms(12500) | zero out(6250) | zero cnt+esum(196)
#define P1_WF   576
#define P1_M    (P1_WF + 64)
#define P1_PHI  (P1_M + 384)
#define P1_NORM (P1_PHI + 12500)
#define P1_ZOUT (P1_NORM + 6250)
#define P1_ZCNT (P1_ZOUT + SCAN_B)
__global__ __launch_bounds__(256) void k_prep1(
    const float* __restrict__ r1, const float* __restrict__ i1,
    __hip_bfloat16* __restrict__ Wb, const float* __restrict__ comb_w,
    const float* __restrict__ lin_w, float* __restrict__ M,
    const float* __restrict__ fre_w, float* __restrict__ Phi,
    const float* __restrict__ hidden, float* __restrict__ norms,
    float* __restrict__ out, int* __restrict__ cnt, float* __restrict__ esum) {
  __shared__ float cs[384], sn[384];
  const int t = threadIdx.x;
  const int b = blockIdx.x;
  if (b < P1_WF) {
    // Wb in MFMA B-frag order
    if (t < 192) sincosf((2.f * PI_F / 192.f) * (float)t, &sn[t], &cs[t]);
    __syncthreads();
    int idx = b * 256 + t;                         // 147456 total
    int n = idx / 768, c = idx - (idx / 768) * 768;
    int k = c >> 8, col = c & 255;
    int isI = col >> 7, j = col & 127;
    const float* ap = (isI ? i1 : r1) + (size_t)k * DIN * EMB + j;
    const float* bp = (isI ? r1 : i1) + (size_t)k * DIN * EMB + j;
    float sgn = isI ? -1.f : 1.f;
    float acc = 0.f;
    int m = 0;
    for (int f = 0; f < DIN; ++f) {
      acc = fmaf(cs[m], ap[(size_t)f * EMB], fmaf(sgn * sn[m], bp[(size_t)f * EMB], acc));
      m += n; if (m >= 192) m -= 192;
    }
    int kc = n >> 5, quad = (n & 31) >> 3, jj = n & 7;
    int lane = quad * 16 + (col & 15);
    Wb[((((k * 6 + kc) * 16 + (col >> 4)) * 64) + lane) * 8 + jj] = __float2bfloat16(acc);
  } else if (b < P1_M) {
    // M[j][j2] = sum_t comb_w[2j][t] * lin_w[t][j2]
    int idx = (b - P1_WF) * 256 + t;               // 16384
    int j = idx >> 7, j2 = idx & 127;
    float acc = 0.f;
    for (int tt = 0; tt < 128; ++tt)
      acc = fmaf(comb_w[(2 * j) * 128 + tt], lin_w[tt * 128 + j2], acc);
    M[idx] = acc;
  } else if (b < P1_PHI) {
    for (int i = t; i < 384; i += 256)
      sincosf((2.f * PI_F / 384.f) * (float)i, &sn[i], &cs[i]);
    __syncthreads();
    int idx = (b - P1_M) * 256 + t;                // 98304
    int slot = idx >> 7, j1 = idx & 127;
    int k = slot >> 8, r = slot & 255;
    int isI = r >> 7;
    int f = k * 128 + (r & 127);
    const float* tp = isI ? sn : cs;
    float sg = isI ? -1.f : 1.f;
    float acc = 0.f;
    int m = 0;
    for (int n = 0; n < 384; ++n) {
      acc = fmaf(sg * tp[m], fre_w[n * 128 + j1], acc);
      m += f; if (m >= 384) m -= 384;
    }
    Phi[slot * 128 + j1] = acc * (1.f / 384.f);
  } else if (b < P1_NORM) {
    // per-node ||hidden[n]||^2
    const int w = t >> 6, lane = t & 63;
    const int n = (b - P1_PHI) * 4 + w;            // 12500*4 = 50000
    const float2 v = ((const float2*)(hidden + (size_t)n * 128))[lane];
    float ss = v.x * v.x + v.y * v.y;
#pragma unroll
    for (int off = 32; off > 0; off >>= 1) ss += __shfl_xor(ss, off, 64);
    if (lane == 0) norms[n] = ss;
  } else if (b < P1_ZOUT) {
    int idx = (b - P1_NORM) * 256 + t;             // 1.6M float4
    ((float4*)out)[idx] = make_float4(0.f, 0.f, 0.f, 0.f);
  } else {
    int idx = (b - P1_ZOUT) * 256 + t;             // 50176
    cnt[idx] = 0;
    if (b == P1_ZOUT && t < 16) esum[t] = 0.f;
  }
}

// ---- P2: g2b(384) | energy+hist(1250) | bb/gb2/look-zero(5) | ck(1)
#define P2_G2  384
#define P2_EN  (P2_G2 + 1250)
#define P2_BB  (P2_EN + 5)
__global__ __launch_bounds__(256) void k_prep2(
    const float* __restrict__ Phi, const float* __restrict__ M,
    __hip_bfloat16* __restrict__ G2b, const float* __restrict__ norms,
    const float* __restrict__ eattr, const float* __restrict__ ett,
    const int* __restrict__ eidx, float* __restrict__ energies,
    float* __restrict__ esum, int* __restrict__ cnt,
    const float* __restrict__ rb1, const float* __restrict__ ib1,
    const float* __restrict__ fre_b, const float* __restrict__ comb_b,
    const float* __restrict__ lin_w, float* __restrict__ bb,
    float* __restrict__ gb2, float* __restrict__ ck,
    unsigned long long* __restrict__ look) {
  const int t = threadIdx.x;
  const int b = blockIdx.x;
  if (b < P2_G2) {
    int idx = b * 256 + t;                         // 98304
    int slot = idx >> 7, j2 = idx & 127;
    float acc = 0.f;
    for (int j1 = 0; j1 < 128; ++j1)
      acc = fmaf(Phi[slot * 128 + j1], M[j1 * 128 + j2], acc);
    int k = slot >> 8, s = slot & 255;
    int kc = s >> 5, quad = (s & 31) >> 3, jj = s & 7;
    G2b[((((k * 8 + kc) * 8 + (j2 >> 4)) * 64) + quad * 16 + (j2 & 15)) * 8 + jj] =
        __float2bfloat16(acc);
  } else if (b < P2_EN) {
    int e = (b - P2_G2) * 256 + t;
    float ss = norms[eidx[e]];
    const float4* a4 = (const float4*)(eattr + (size_t)e * 32);
#pragma unroll
    for (int i = 0; i < 8; ++i) {
      float4 v = a4[i];
      ss += v.x * v.x + v.y * v.y + v.z * v.z + v.w * v.w;
    }
    const float4* t4 = (const float4*)(ett + (size_t)e * 32);
#pragma unroll
    for (int i = 0; i < 8; ++i) {
      float4 v = t4[i];
      ss += v.x * v.x + v.y * v.y + v.z * v.z + v.w * v.w;
    }
    float en = 192.f * ss;
    energies[e] = en;
    float tot = en;
#pragma unroll
    for (int off = 32; off > 0; off >>= 1) tot += __shfl_down(tot, off, 64);
    if ((t & 63) == 0) atomicAdd(esum, tot);
    atomicAdd(&cnt[eidx[NEDGES + e]], 1);          // histogram
  } else if (b < P2_BB) {
    int idx = (b - P2_EN) * 256 + t;               // 1280
    if (idx < 768) {
      int k = idx >> 8, r = idx & 255;
      bb[idx] = (r >= 128) ? ib1[k * 128 + (r & 127)] : rb1[k * 128 + r];
    } else if (idx < 896) {
      int j2 = idx - 768;
      float acc = 0.f;
      for (int j = 0; j < 128; ++j) acc += fre_b[j] * M[j * 128 + j2];
      for (int tt = 0; tt < 128; ++tt) acc += comb_b[tt] * lin_w[tt * 128 + j2];
      gb2[j2] = acc;
    } else if (idx < 1152) {
      look[idx - 896] = 0ULL;
    }
  } else {
    // ck[k] = (ssr_k @ PhiR_k + ssi_k @ PhiI_k) @ M   (single block)
    __shared__ float ckphi[NB][128];
    if (t < 128) {
#pragma unroll
      for (int k = 0; k < NB; ++k) {
        float acc = 0.f;
        for (int j = 0; j < 128; ++j) {
          float vr = rb1[k * 128 + j];
          vr = fmaxf(vr, 0.f); vr = (vr > LAM) ? vr - LAM : 0.f;
          float vi = ib1[k * 128 + j];
          vi = fmaxf(vi, 0.f); vi = (vi > LAM) ? vi - LAM : 0.f;
          acc += vr * Phi[(k * 256 + j) * 128 + t] +
                 vi * Phi[(k * 256 + 128 + j) * 128 + t];
        }
        ckphi[k][t] = acc;
      }
    }
    __syncthreads();
    if (t < 128) {
#pragma unroll
      for (int k = 0; k < NB; ++k) {
        float acc = 0.f;
        for (int j1 = 0; j1 < 128; ++j1)
          acc = fmaf(ckphi[k][j1], M[j1 * 128 + t], acc);
        ck[k * 128 + t] = acc;
      }
    }
  }
}

// ---- P3: single-pass decoupled-lookback exclusive scan -> cur ----
__global__ __launch_bounds__(256) void k_scan(const int* __restrict__ cnt,
                                              int* __restrict__ cur,
                                              unsigned long long* __restrict__ look) {
  __shared__ int sm[256];
  __shared__ int xoff;
  const int t = threadIdx.x;
  const int b = blockIdx.x;
  int i = b * 256 + t;
  int v = cnt[i];
  sm[t] = v;
  __syncthreads();
#pragma unroll
  for (int off = 1; off < 256; off <<= 1) {
    int x = (t >= off) ? sm[t - off] : 0;
    __syncthreads();
    sm[t] += x;
    __syncthreads();
  }
  if (t == 0) {
    int total = sm[255];
    if (b == 0) {
      __hip_atomic_store(&look[0], (2ULL << 32) | (unsigned)total,
                         __ATOMIC_RELEASE, __HIP_MEMORY_SCOPE_AGENT);
      xoff = 0;
    } else {
      __hip_atomic_store(&look[b], (1ULL << 32) | (unsigned)total,
                         __ATOMIC_RELEASE, __HIP_MEMORY_SCOPE_AGENT);
      unsigned run = 0;
      int p = b - 1;
      while (true) {
        unsigned long long s = __hip_atomic_load(&look[p], __ATOMIC_ACQUIRE,
                                                 __HIP_MEMORY_SCOPE_AGENT);
        unsigned st = (unsigned)(s >> 32);
        if (st == 0) { __builtin_amdgcn_s_sleep(8); continue; }
        run += (unsigned)s;
        if (st == 2) break;
        --p;
      }
      __hip_atomic_store(&look[b], (2ULL << 32) | (unsigned)(run + (unsigned)total),
                         __ATOMIC_RELEASE, __HIP_MEMORY_SCOPE_AGENT);
      xoff = (int)run;
    }
  }
  __syncthreads();
  cur[i] = sm[t] - v + xoff;
}

// ---- P4: fill sorted edge ids ----
__global__ __launch_bounds__(256) void k_fill(const int* __restrict__ eidx,
                                              int* __restrict__ cur,
                                              int* __restrict__ eids) {
  int e = blockIdx.x * 256 + threadIdx.x;
  int pos = atomicAdd(&cur[eidx[NEDGES + e]], 1);
  eids[pos] = e;
}

// ---- main edge kernel: 64 dst-sorted edges/block, 512 threads (8 waves) ----
#define XS_STR 200
#define OS_STR 264
#define ZS_STR 130
__global__ __launch_bounds__(512, 4) void k_edges(
    const float* __restrict__ hidden, const float* __restrict__ eattr,
    const float* __restrict__ ett, const float* __restrict__ alpha,
    const int* __restrict__ eidx, const int* __restrict__ eids,
    const __hip_bfloat16* __restrict__ Wb, const __hip_bfloat16* __restrict__ G2b,
    const float* __restrict__ bb, const float* __restrict__ gb2,
    const float* __restrict__ ck, const float* __restrict__ energies,
    const float* __restrict__ esum, float* __restrict__ accum) {
  __shared__ __align__(16) char smem[64 * XS_STR * 2 + 64 * OS_STR * 2];
  short* Xs = (short*)smem;
  short* Os = (short*)(smem + 64 * XS_STR * 2);
  float* Zs = (float*)smem;
  __shared__ float maskf[3][64];
  __shared__ int eid_s[64], srcs[64], dsts[64];
  __shared__ int tileact[3];

  const int t = threadIdx.x;
  const int e0 = blockIdx.x * 64;
  const int lane = t & 63, w = t >> 6;
  const int quad = lane >> 4, lc = lane & 15;

  // prefetch band-0 Wb B-frags (independent of everything; overlaps gather)
  v8s wpre[12];
#pragma unroll
  for (int kc = 0; kc < 6; ++kc)
#pragma unroll
    for (int ntl = 0; ntl < 2; ++ntl)
      wpre[kc * 2 + ntl] =
          *(const v8s*)(const void*)(Wb + (((kc * 16 + 2 * w + ntl) * 64) + lane) * 8);

  if (t < 3) tileact[t] = 0;
  if (t < 64) {
    int eid = eids[e0 + t];
    eid_s[t] = eid;
    srcs[t] = eidx[eid];
    dsts[t] = eidx[NEDGES + eid];                  // non-decreasing across t
    float en = energies[eid];
    float es = *esum;
#pragma unroll
    for (int k = 0; k < NB; ++k) {
      float a = alpha[k];
      float factor = (2.f * (k + 1) - 1.f) / (2.f * NB);
      float Q = a * factor * es;
      float b = es / (a * (2.f * NB));
      bool m = (en >= Q - b) && (en <= Q + b);
      maskf[k][t] = m ? 1.f : 0.f;
      if (m) atomicOr(&tileact[k], 1);
    }
  }
  __syncthreads();

  // gather x = [hidden[src] | edge_attr | edge_time_emb] -> bf16 LDS
  {
    float4 hv[4]; int he[4], hc[4];
#pragma unroll
    for (int it = 0; it < 4; ++it) {
      int i = t + it * 512;                         // < 2048
      he[it] = i >> 5; hc[it] = i & 31;
      hv[it] = *(const float4*)(hidden + (size_t)srcs[he[it]] * 128 + hc[it] * 4);
    }
    float4 fv[2]; int fe[2], fq[2];
#pragma unroll
    for (int it = 0; it < 2; ++it) {
      int i = t + it * 512;                         // < 1024
      fe[it] = i >> 4; fq[it] = i & 15;
      if (fq[it] < 8) fv[it] = ((const float4*)(eattr + (size_t)eid_s[fe[it]] * 32))[fq[it]];
      else            fv[it] = ((const float4*)(ett + (size_t)eid_s[fe[it]] * 32))[fq[it] - 8];
    }
#pragma unroll
    for (int it = 0; it < 4; ++it) {
      unsigned* p = (unsigned*)&Xs[he[it] * XS_STR + hc[it] * 4];
      p[0] = pk2(hv[it].x, hv[it].y); p[1] = pk2(hv[it].z, hv[it].w);
    }
#pragma unroll
    for (int it = 0; it < 2; ++it) {
      unsigned* p = (unsigned*)&Xs[fe[it] * XS_STR + 128 + fq[it] * 4];
      p[0] = pk2(fv[it].x, fv[it].y); p[1] = pk2(fv[it].z, fv[it].w);
    }
  }
  __syncthreads();

  v4f acc2[4];
#pragma unroll
  for (int mt = 0; mt < 4; ++mt)
#pragma unroll
    for (int r = 0; r < 4; ++r) acc2[mt][r] = 0.f;

#pragma unroll
  for (int k = 0; k < NB; ++k) {
    if (!tileact[k]) continue;                      // block-uniform
    v4f accA[4][2];
#pragma unroll
    for (int mt = 0; mt < 4; ++mt)
#pragma unroll
      for (int n = 0; n < 2; ++n)
#pragma unroll
        for (int r = 0; r < 4; ++r) accA[mt][n][r] = 0.f;

#pragma unroll
    for (int kc = 0; kc < 6; ++kc) {
      v8s af[4];
#pragma unroll
      for (int mt = 0; mt < 4; ++mt)
        af[mt] = *(const v8s*)&Xs[(mt * 16 + lc) * XS_STR + kc * 32 + quad * 8];
      const __hip_bfloat16* wp = Wb + ((((k * 6 + kc) * 16 + 2 * w) * 64) + lane) * 8;
#pragma unroll
      for (int ntl = 0; ntl < 2; ++ntl) {
        v8s bfr = (k == 0) ? wpre[kc * 2 + ntl]
                           : *(const v8s*)(const void*)(wp + ntl * 512);
#pragma unroll
        for (int mt = 0; mt < 4; ++mt)
          accA[mt][ntl] =
              __builtin_amdgcn_mfma_f32_16x16x32_bf16(af[mt], bfr, accA[mt][ntl], 0, 0, 0);
      }
    }
    __syncthreads();  // protect Os WAR vs previous band's stage B reads
    // nonlinearity -> Os (bf16)
#pragma unroll
    for (int mt = 0; mt < 4; ++mt)
#pragma unroll
      for (int ntl = 0; ntl < 2; ++ntl) {
        int col = w * 32 + ntl * 16 + lc;
        float bbv = bb[k * 256 + col];
#pragma unroll
        for (int reg = 0; reg < 4; ++reg) {
          int row = mt * 16 + quad * 4 + reg;
          float mk = maskf[k][row];
          float v = fmaf(mk, accA[mt][ntl][reg], bbv);
          v = fmaxf(v, 0.f);
          v = (v > LAM) ? v - LAM : 0.f;
          __hip_bfloat16 h = __float2bfloat16(v);
          Os[row * OS_STR + col] = *reinterpret_cast<short*>(&h);
        }
      }
    __syncthreads();
    // stage B: acc2 += O' @ G2_band ; wave w -> cols w*16..w*16+15
#pragma unroll
    for (int kc = 0; kc < 8; ++kc) {
      v8s of[4];
#pragma unroll
      for (int mt = 0; mt < 4; ++mt)
        of[mt] = *(const v8s*)&Os[(mt * 16 + lc) * OS_STR + kc * 32 + quad * 8];
      const __hip_bfloat16* gp = G2b + ((((k * 8 + kc) * 8 + w) * 64) + lane) * 8;
      v8s bfr = *(const v8s*)(const void*)gp;
#pragma unroll
      for (int mt = 0; mt < 4; ++mt)
        acc2[mt] = __builtin_amdgcn_mfma_f32_16x16x32_bf16(of[mt], bfr, acc2[mt], 0, 0, 0);
    }
  }

  // ---- epilogue: z -> Zs (LDS), then segmented reduce (2 waves) + atomics ----
  __syncthreads();                                  // Xs/Os dead; reuse as Zs
  {
    int col = w * 16 + lc;
    float base = gb2[col];
#pragma unroll
    for (int k = 0; k < NB; ++k)
      if (!tileact[k]) base += ck[k * 128 + col];
#pragma unroll
    for (int mt = 0; mt < 4; ++mt)
#pragma unroll
      for (int reg = 0; reg < 4; ++reg) {
        int row = mt * 16 + quad * 4 + reg;
        Zs[row * ZS_STR + col] = acc2[mt][reg] + base;
      }
  }
  __syncthreads();
  if (w < 2) {
    int c = 2 * lane;
    int r0 = w * 32;
    float s0 = 0.f, s1 = 0.f;
#pragma unroll
    for (int r = 0; r < 32; ++r) {
      int row = r0 + r;
      s0 += Zs[row * ZS_STR + c];
      s1 += Zs[row * ZS_STR + c + 1];
      int d = dsts[row];
      if (r == 31 || dsts[row + 1] != d) {
        atomic2(accum + (size_t)d * 128 + c, s0, s1);
        s0 = 0.f; s1 = 0.f;
      }
    }
  }
}

// node kernel: acc + boundary@lin_w + lin_b -> LayerNorm -> relu
__global__ __launch_bounds__(256) void k_nodes(const float* __restrict__ boundary,
                                               const float* __restrict__ lin_w,
                                               const float* __restrict__ lin_b,
                                               const float* __restrict__ ln_g,
                                               const float* __restrict__ ln_b,
                                               float* __restrict__ out) {
  __shared__ float lw[32][128];
  const int t = threadIdx.x;
  const int w = t >> 6, lane = t & 63;
  const int n = blockIdx.x * 4 + w;
  float a0 = out[(size_t)n * 128 + lane] + lin_b[lane];
  float a1 = out[(size_t)n * 128 + 64 + lane] + lin_b[64 + lane];
  for (int cb = 0; cb < 128; cb += 32) {
    __syncthreads();
#pragma unroll
    for (int it = 0; it < 16; ++it) {
      int i = t + it * 256;
      lw[i >> 7][i & 127] = lin_w[(cb + (i >> 7)) * 128 + (i & 127)];
    }
    __syncthreads();
#pragma unroll
    for (int r = 0; r < 32; ++r) {
      float bv = boundary[(size_t)n * 128 + cb + r];
      a0 = fmaf(bv, lw[r][lane], a0);
      a1 = fmaf(bv, lw[r][64 + lane], a1);
    }
  }
  float s = a0 + a1, sq = a0 * a0 + a1 * a1;
#pragma unroll
  for (int off = 32; off > 0; off >>= 1) {
    s += __shfl_xor(s, off, 64);
    sq += __shfl_xor(sq, off, 64);
  }
  float mu = s * (1.f / 128.f);
  float var = sq * (1.f / 128.f) - mu * mu;
  float rs = 1.f / sqrtf(var + LN_EPS);
  float y0 = (a0 - mu) * rs * ln_g[lane] + ln_b[lane];
  float y1 = (a1 - mu) * rs * ln_g[64 + lane] + ln_b[64 + lane];
  out[(size_t)n * 128 + lane] = fmaxf(y0, 0.f);
  out[(size_t)n * 128 + 64 + lane] = fmaxf(y1, 0.f);
}

extern "C" void kernel_launch(void* const* d_in, const int* in_sizes, int n_in,
                              void* d_out, int out_size, void* d_ws, size_t ws_size,
                              hipStream_t stream) {
  const float* hidden   = (const float*)d_in[0];
  const float* eattr    = (const float*)d_in[1];
  const float* ett      = (const float*)d_in[2];
  const float* boundary = (const float*)d_in[3];
  const float* alpha    = (const float*)d_in[4];
  const float* r1       = (const float*)d_in[5];
  const float* i1       = (const float*)d_in[6];
  const float* rb1      = (const float*)d_in[7];
  const float* ib1      = (const float*)d_in[8];
  const float* fre_w    = (const float*)d_in[9];
  const float* fre_b    = (const float*)d_in[10];
  const float* comb_w   = (const float*)d_in[11];
  const float* comb_b   = (const float*)d_in[12];
  const float* lin_w    = (const float*)d_in[13];
  const float* lin_b    = (const float*)d_in[14];
  const float* ln_g     = (const float*)d_in[15];
  const float* ln_b     = (const float*)d_in[16];
  const int*   eidx     = (const int*)d_in[17];
  float* ws  = (float*)d_ws;
  float* out = (float*)d_out;
  __hip_bfloat16* Wb  = (__hip_bfloat16*)(ws + WS_WB);
  __hip_bfloat16* G2b = (__hip_bfloat16*)(ws + WS_G2B);
  int* cnt  = (int*)(ws + WS_CNT);
  int* cur  = (int*)(ws + WS_CUR);
  unsigned long long* look = (unsigned long long*)(ws + WS_LOOK);
  int* eids = (int*)(ws + WS_EIDS);

  k_prep1<<<P1_ZCNT, 256, 0, stream>>>(r1, i1, Wb, comb_w, lin_w, ws + WS_M,
                                       fre_w, ws + WS_PHI, hidden, ws + WS_NORM,
                                       out, cnt, ws + WS_ESUM);
  k_prep2<<<P2_BB + 1, 256, 0, stream>>>(ws + WS_PHI, ws + WS_M, G2b, ws + WS_NORM,
                                         eattr, ett, eidx, ws + WS_EN, ws + WS_ESUM,
                                         cnt, rb1, ib1, fre_b, comb_b, lin_w,
                                         ws + WS_BB, ws + WS_GB2, ws + WS_CK, look);
  k_scan<<<SCAN_B, 256, 0, stream>>>(cnt, cur, look);
  k_fill<<<NEDGES / 256, 256, 0, stream>>>(eidx, cur, eids);
  k_edges<<<NEDGES / 64, 512, 0, stream>>>(hidden, eattr, ett, alpha, eidx, eids,
                                           Wb, G2b, ws + WS_BB, ws + WS_GB2,
                                           ws + WS_CK, ws + WS_EN, ws + WS_ESUM, out);
  k_nodes<<<NNODES / 4, 256, 0, stream>>>(boundary, lin_w, lin_b, ln_g, ln_b, out);
}